// Round 8
// baseline (1783.197 us; speedup 1.0000x reference)
//
#include <hip/hip_runtime.h>

// Autoregressive masked net sampler.
//  - output col i == sampling-time x[:,i]  (masks: out i depends on spins < i only)
//  - spin blocks of KB=8: history part = dense GEMM (MFMA f16), intra-block part
//    sequential per-row (rows independent -> no grid sync).
// R9: split kernels (hist | seq), 1154us, strictly serial on one stream.
// R10/R11: fused hist(m+1) into seq(m) as helper waves; REGRESSED to 1700us.
//     Cause per counters: launch_bounds(512,4) -> compiler snapped to 64 VGPR
//     (seq needs ~88, helper loop ~75+) -> inner-loop scratch spills (FETCH
//     141->194MB, WRITE 41->61MB = spill traffic), MfmaUtil 6.7%. Also per-(t,L)
//     tail-B global reads re-fetched 8x and got L2-evicted by helper AH stream.
// R12 (this): same fusion, three mechanical fixes:
//     1) launch_bounds(512) -- no wave-min -> VGPR free (~112-128), 2 WG/CU.
//     2) tail B (t-invariant, 20KB/WG) loaded to LDS once at WG start; phases
//        read it via ds_read_b128 (no global dep, no L2-thrash exposure).
//     3) s_setprio(1) on seq wave only (critical chain vs throughput helpers).

#define NS   64          // spins
#define HC   20          // hidden channels per spin
#define HTOT 1280        // NS*HC
#define NB   16384       // batch
#define KB   8           // spins per block (8 blocks)
#define BT   16          // batch rows per seq wave (MFMA N-tile)

typedef _Float16 f16;
typedef _Float16 f16x2 __attribute__((ext_vector_type(2)));
typedef _Float16 f16x4 __attribute__((ext_vector_type(4)));
typedef _Float16 f16x8 __attribute__((ext_vector_type(8)));
typedef float f32x4 __attribute__((ext_vector_type(4)));
typedef unsigned int u32x4 __attribute__((ext_vector_type(4)));

static __device__ __forceinline__ float sigm(float z) {
  return __builtin_amdgcn_rcpf(1.0f + __expf(-z));
}

static __device__ __forceinline__ unsigned pk2(float a, float b) {
  f16x2 t;
  t[0] = (f16)a;
  t[1] = (f16)b;
  return __builtin_bit_cast(unsigned, t);
}

// intra-wave LDS sync: drain ds ops; memory clobber pins mem-op order.
static __device__ __forceinline__ void wsync() {
  __asm__ volatile("s_waitcnt lgkmcnt(0)" ::: "memory");
}

// ---------------------------------------------------------------------------
// prep: build masked f16 weights, pre-swizzled to MFMA A-fragment order.
// Fragment order: lane = quad*16 + row15, elems 8; col = ks*32 + quad*8 + e.
//  WpT [L][rt=row/16][ks=0..39][512]    row=j_o*20+ch_o, mask j_i<=j_o (hist A)
//  WsT2[L][i][tile][ks=0..9][512]       cols rel to HC*(i&~7)-160 (tail+intra),
//                                       ch padded ->32, col<0 => 0 (seq A)
//  W1T [i][tile][ks=0..1][512]          cols = spins, mask c<i (seq L1 A)
//  W6bT[m*8+t][512]                     16 tp rows x 32 k, mask t<=tp,k<20 (z6 A)
//  W6T [m][ks=0..39][512]               16 tp rows (8 real), mask j_i<=I+tp
// ---------------------------------------------------------------------------
__global__ __launch_bounds__(256) void prep(
    const float* __restrict__ W1, const float* __restrict__ W2,
    const float* __restrict__ W3, const float* __restrict__ W4,
    const float* __restrict__ W5, const float* __restrict__ W6,
    f16* __restrict__ WpT, f16* __restrict__ WsT2, f16* __restrict__ W1T,
    f16* __restrict__ W6bT, f16* __restrict__ W6T) {
  __shared__ float row[HTOT];
  int bid = blockIdx.x;
  if (bid < 4 * HTOT) {
    int L = bid / HTOT, cp = bid % HTOT;
    int j_o = cp / HC, ch_o = cp % HC;
    const float* Wsrc = (L == 0) ? W2 : (L == 1) ? W3 : (L == 2) ? W4 : W5;
    const float* src = Wsrc + (size_t)(ch_o * NS + j_o) * HTOT;
    for (int k = threadIdx.x; k < HTOT; k += 256) row[k] = src[k];
    __syncthreads();
    // WpT: this source row is A-row cp -> rt = cp>>4, row15 = cp&15
    {
      int rt = cp >> 4, rl = cp & 15;
      f16* dwp = WpT + (size_t)(L * 80 + rt) * 40 * 512;
      for (int xp = threadIdx.x; xp < HTOT; xp += 256) {
        int j_i = xp / HC, ch_i = xp % HC;
        f16 v = (f16)((j_i <= j_o) ? row[ch_i * NS + j_i] : 0.0f);
        int ks = xp >> 5, q = (xp >> 3) & 3, e = xp & 7;
        dwp[ks * 512 + (q * 16 + rl) * 8 + e] = v;
      }
    }
    // WsT2: A-row ch_o of spin j_o, cols base HC*(j_o&~7)-160 (prev block + intra)
    {
      int base = HC * (j_o & ~7) - 160;
      int tile = ch_o >> 4, tl = ch_o & 15;
      f16* dws = WsT2 + (size_t)(((L * NS + j_o) * 2 + tile) * 10) * 512;
      for (int kr = threadIdx.x; kr < 320; kr += 256) {
        int xp = base + kr;
        f16 v = (f16)0.0f;
        if (xp >= 0) {
          int j_i = xp / HC, ch_i = xp % HC;
          v = (f16)((j_i <= j_o) ? row[ch_i * NS + j_i] : 0.0f);
        }
        int ks = kr >> 5, q = (kr >> 3) & 3, e = kr & 7;
        dws[ks * 512 + (q * 16 + tl) * 8 + e] = v;
      }
      if (ch_o < 12) {  // zero pad rows ch=20..31 (tile1 rows 4..15)
        int zl = (20 + ch_o) & 15;
        f16* dz = WsT2 + (size_t)(((L * NS + j_o) * 2 + 1) * 10) * 512;
        for (int kr = threadIdx.x; kr < 320; kr += 256) {
          int ks = kr >> 5, q = (kr >> 3) & 3, e = kr & 7;
          dz[ks * 512 + (q * 16 + zl) * 8 + e] = (f16)0.0f;
        }
      }
    }
  } else if (bid < 4 * HTOT + NS) {
    int j_o = bid - 4 * HTOT;
    for (int idx = threadIdx.x; idx < 32 * 64; idx += 256) {
      int ch = idx >> 6, c = idx & 63;
      float v = (ch < HC && c < j_o) ? W1[((size_t)ch * NS + j_o) * NS + c] : 0.0f;
      int tile = ch >> 4, tl = ch & 15, ks = c >> 5, q = (c >> 3) & 3, e = c & 7;
      W1T[(size_t)((j_o * 2 + tile) * 2 + ks) * 512 + (q * 16 + tl) * 8 + e] = (f16)v;
    }
  } else if (bid < 4 * HTOT + NS + 8) {
    int m = bid - (4 * HTOT + NS);
    int I = m * KB;
    for (int idx = threadIdx.x; idx < 8 * 16 * 32; idx += 256) {
      int t = idx >> 9, tp = (idx >> 5) & 15, k = idx & 31;
      float v = (tp < 8 && k < HC && t <= tp)
                    ? W6[(size_t)(I + tp) * HTOT + k * NS + (I + t)]
                    : 0.0f;
      int q = k >> 3, e = k & 7;
      W6bT[(size_t)(m * 8 + t) * 512 + (q * 16 + tp) * 8 + e] = (f16)v;
    }
  } else {
    int m = bid - (4 * HTOT + NS + 8);
    int I = m * KB;
    for (int idx = threadIdx.x; idx < 16 * HTOT; idx += 256) {
      int tp = idx / HTOT, xp = idx % HTOT;
      int j_i = xp / HC, ch_i = xp % HC;
      float v = (tp < 8 && j_i <= I + tp)
                    ? W6[(size_t)(I + tp) * HTOT + ch_i * NS + j_i]
                    : 0.0f;
      int ks = xp >> 5, q = (xp >> 3) & 3, e = xp & 7;
      W6T[(size_t)(m * 40 + ks) * 512 + (q * 16 + tp) * 8 + e] = (f16)v;
    }
  }
}

// ---------------------------------------------------------------------------
// fused: wave0 = seq for block m (16 batch cols); waves1..7 = history GEMM for
// block m+1 over k < 160*m (blocks 0..m-1, all written by previous launches).
//  seq: Zg(m) [blocks 0..m-2, from ZgR] post-added + per-phase 5-ks tail over
//       block m-1 with B-frags staged in LDS once (t-invariant).
//  helpers: units = hist tiles (4L x 2 rowhalves x nr/32 cols) + z6 (nr/64).
// ---------------------------------------------------------------------------
__global__ __launch_bounds__(512) void fused(
    const f16* __restrict__ WpT, const f16* __restrict__ W6T,
    const f16* __restrict__ WsT2, const f16* __restrict__ W1T,
    const f16* __restrict__ W6bT, f16* __restrict__ AH,
    const float* __restrict__ ZgR, float* __restrict__ ZgW,
    const float* __restrict__ Zg6R, float* __restrict__ Zg6W,
    f16* __restrict__ s_ws, const float* __restrict__ u,
    float* __restrict__ outp, int I, int BS, int b0) {
  __shared__ __align__(16) f16 aL[5][BT][184];   // 29440 B
  __shared__ __align__(16) f16 sL[BT][72];       // 2304 B
  __shared__ __align__(16) f16 tailB[4 * 5 * 512];  // 20480 B -> 52224 B total

  const int wid = threadIdx.x >> 6;
  const int lane = threadIdx.x & 63;
  const int l15 = lane & 15;
  const int quad = lane >> 4;
  const int m = I >> 3;
  const int G32 = (HC * I) >> 5;   // k-steps over blocks 0..m-1
  const int nr = gridDim.x * BT;

  if (wid != 0) {
    // ================= helper waves: Zg(m+1)/Zg6(m+1) =================
    if (I >= NS - KB || G32 == 0) return;  // no next block / empty history
    const int NH = 7 * gridDim.x;
    const int per = nr >> 5;          // 32-col tiles per (L, wm)
    const int UH = nr >> 2;           // 4L * 2wm * per
    const int UZ = nr >> 6;           // z6 units (64 cols each)
    int hid = blockIdx.x * 7 + wid - 1;
    for (int uu = hid; uu < UH + UZ; uu += NH) {
      if (uu < UH) {
        const int L = uu / (2 * per);
        const int r2 = uu % (2 * per);
        const int wm = r2 / per;
        const int bc = (r2 % per) * 32;
        f32x4 acc[5][2];
#pragma unroll
        for (int mt = 0; mt < 5; ++mt) {
          acc[mt][0] = (f32x4){0.f, 0.f, 0.f, 0.f};
          acc[mt][1] = (f32x4){0.f, 0.f, 0.f, 0.f};
        }
        const f16* ap =
            WpT + (size_t)((L * 80 + 10 * (m + 1) + 5 * wm) * 40) * 512 + lane * 8;
        const f16* bp = AH + ((size_t)(L * 160 + quad) * BS + bc + l15) * 8;
#pragma unroll 2
        for (int ks = 0; ks < G32; ++ks) {
          f16x8 bf0 = *(const f16x8*)(bp);
          f16x8 bf1 = *(const f16x8*)(bp + 128);
          f16x8 af[5];
#pragma unroll
          for (int mt = 0; mt < 5; ++mt)
            af[mt] = *(const f16x8*)(ap + (size_t)mt * 40 * 512);
#pragma unroll
          for (int mt = 0; mt < 5; ++mt) {
            acc[mt][0] = __builtin_amdgcn_mfma_f32_16x16x32_f16(af[mt], bf0, acc[mt][0], 0, 0, 0);
            acc[mt][1] = __builtin_amdgcn_mfma_f32_16x16x32_f16(af[mt], bf1, acc[mt][1], 0, 0, 0);
          }
          ap += 512;
          bp += (size_t)4 * BS * 8;
        }
#pragma unroll
        for (int mt = 0; mt < 5; ++mt)
#pragma unroll
          for (int nt = 0; nt < 2; ++nt)
#pragma unroll
            for (int r = 0; r < 4; ++r)
              ZgW[(size_t)(L * 160 + wm * 80 + mt * 16 + quad * 4 + r) * BS +
                  bc + nt * 16 + l15] = acc[mt][nt][r];
      } else {
        const int v = uu - UH;
#pragma unroll
        for (int b16 = 0; b16 < 4; ++b16) {
          const int bc = v * 64 + b16 * 16;
          f32x4 acc = (f32x4){0.f, 0.f, 0.f, 0.f};
          const f16* ap = W6T + (size_t)((m + 1) * 40) * 512 + lane * 8;
          const f16* bp = AH + ((size_t)(4 * 160 + quad) * BS + bc + l15) * 8;
#pragma unroll 2
          for (int ks = 0; ks < G32; ++ks) {
            acc = __builtin_amdgcn_mfma_f32_16x16x32_f16(
                *(const f16x8*)ap, *(const f16x8*)bp, acc, 0, 0, 0);
            ap += 512;
            bp += (size_t)4 * BS * 8;
          }
#pragma unroll
          for (int r = 0; r < 4; ++r)
            Zg6W[(size_t)(quad * 4 + r) * BS + bc + l15] = acc[r];
        }
      }
    }
    return;
  }

  // ========================= seq wave (wave0) =========================
  __builtin_amdgcn_s_setprio(1);  // critical chain; helpers are throughput waves

  const int bcol = blockIdx.x * BT + l15;
  const int bg = b0 + bcol;
  const int gP = 20 * (m - 1);  // AH g-base of prev block (tail B)

  // early global loads: u for all 8 spins, z6 accumulator init
  float uv[KB];
#pragma unroll
  for (int t = 0; t < KB; ++t) uv[t] = u[(size_t)(I + t) * NB + bg];
  f32x4 acc6 = (f32x4){0.f, 0.f, 0.f, 0.f};
  if (m >= 2) {
#pragma unroll
    for (int r = 0; r < 4; ++r)
      acc6[r] = Zg6R[(size_t)(quad * 4 + r) * BS + bcol];
  }
  if (m >= 1) {  // z6 tail: block m-1 via W6T[m] slab [5(m-1),5m)
    const f16* a6p = W6T + ((size_t)(m * 40) + 5 * (m - 1)) * 512 + lane * 8;
#pragma unroll
    for (int ks = 0; ks < 5; ++ks) {
      f16x8 bf = *(const f16x8*)(AH + ((size_t)(4 * 160 + gP + 4 * ks + quad) * BS + bcol) * 8);
      f16x8 af = *(const f16x8*)(a6p + ks * 512);
      acc6 = __builtin_amdgcn_mfma_f32_16x16x32_f16(af, bf, acc6, 0, 0, 0);
    }
  }

  // stage t-invariant tail B (prev block, 4 layers x 5 ks) into LDS, once
  if (m >= 1) {
#pragma unroll
    for (int L4 = 0; L4 < 4; ++L4)
#pragma unroll
      for (int ks = 0; ks < 5; ++ks) {
        f16x8 bf = *(const f16x8*)(AH + ((size_t)(L4 * 160 + gP + 4 * ks + quad) * BS + bcol) * 8);
        *(f16x8*)&tailB[(L4 * 5 + ks) * 512 + lane * 8] = bf;
      }
  }

  // zero LDS (masked-weight / K-pad tails must read as 0)
  {
    f16x8 z = {};
    f16x8* pa = (f16x8*)&aL[0][0][0];
    for (int k = lane; k < (5 * BT * 184) / 8; k += 64) pa[k] = z;
    f16x8* ps = (f16x8*)&sL[0][0];
    for (int k = lane; k < (BT * 72) / 8; k += 64) ps[k] = z;
  }
  wsync();

  // load sampled-bit history j < I
  for (int c8 = quad; c8 < (I >> 3); c8 += 4) {
    f16x8 v = *(const f16x8*)(s_ws + (size_t)(blockIdx.x * BT + l15) * NS + c8 * 8);
    *(f16x8*)&sL[l15][c8 * 8] = v;
  }
  wsync();

  float bitv = 0.0f;  // freshest sampled bit (spin I+t-1), per batch-column

#pragma unroll
  for (int t = 0; t < KB; ++t) {
    const int i = I + t;

    // ---- prefetch this t's Zg rows for all 4 hidden layers (post-added) ----
    float zg0[4][4], zg1[4][4];
#pragma unroll
    for (int L = 0; L < 4; ++L)
#pragma unroll
      for (int r = 0; r < 4; ++r) {
        zg0[L][r] = (m >= 2)
            ? ZgR[(size_t)(L * 160 + t * HC + quad * 4 + r) * BS + bcol] : 0.f;
        zg1[L][r] = (m >= 2 && quad == 0)
            ? ZgR[(size_t)(L * 160 + t * HC + 16 + r) * BS + bcol] : 0.f;
      }

    // ---- layer 1: z[32ch x 16b] = W1(i) (32x64) . sL (64x16) ----
    {
      f32x4 z0 = (f32x4){0.f, 0.f, 0.f, 0.f};
      f32x4 z1 = (f32x4){0.f, 0.f, 0.f, 0.f};
      const int KS1 = (i + 31) >> 5;
      const f16* w0 = W1T + (size_t)(i * 2) * 2 * 512 + lane * 8;
      for (int ks = 0; ks < KS1; ++ks) {
        f16x8 bf = *(const f16x8*)&sL[l15][quad * 8 + 32 * ks];
        if (t > 0 && ks == ((i - 1) >> 5) && quad == (((I & 31) + t - 1) >> 3))
          bf[(t - 1) & 7] = (f16)bitv;  // freshest bit, not yet LDS-visible
        f16x8 a0 = *(const f16x8*)(w0 + ks * 512);
        f16x8 a1 = *(const f16x8*)(w0 + (2 + ks) * 512);
        z0 = __builtin_amdgcn_mfma_f32_16x16x32_f16(a0, bf, z0, 0, 0, 0);
        z1 = __builtin_amdgcn_mfma_f32_16x16x32_f16(a1, bf, z1, 0, 0, 0);
      }
      f16x4 o0;
#pragma unroll
      for (int r = 0; r < 4; ++r) o0[r] = (f16)sigm(z0[r]);
      *(f16x4*)&aL[0][l15][t * HC + quad * 4] = o0;
      if (quad == 0) {
        f16x4 o1;
#pragma unroll
        for (int r = 0; r < 4; ++r) o1[r] = (f16)sigm(z1[r]);
        *(f16x4*)&aL[0][l15][t * HC + 16] = o1;
      }
    }
    wsync();

    // ---- layers 2..5: z = tail(block m-1, B from LDS) + intra + Zg ----
    const int KS = (HC * (t + 1) + 31) >> 5;  // compile-time under unroll
    float a5o0[4], a5o1[4];
#pragma unroll
    for (int L = 0; L < 4; ++L) {
      f32x4 z0 = (f32x4){0.f, 0.f, 0.f, 0.f};
      f32x4 z1 = (f32x4){0.f, 0.f, 0.f, 0.f};
      const f16* wb = WsT2 + (size_t)((L * NS + i) * 2) * 10 * 512 + lane * 8;
      if (m >= 1) {  // tail: 5 ks, B from LDS (staged once, t-invariant)
#pragma unroll
        for (int ks = 0; ks < 5; ++ks) {
          f16x8 bf = *(const f16x8*)&tailB[(L * 5 + ks) * 512 + lane * 8];
          f16x8 a0 = *(const f16x8*)(wb + ks * 512);
          f16x8 a1 = *(const f16x8*)(wb + (10 + ks) * 512);
          z0 = __builtin_amdgcn_mfma_f32_16x16x32_f16(a0, bf, z0, 0, 0, 0);
          z1 = __builtin_amdgcn_mfma_f32_16x16x32_f16(a1, bf, z1, 0, 0, 0);
        }
      }
#pragma unroll
      for (int ks = 0; ks < KS; ++ks) {
        f16x8 bf = *(const f16x8*)&aL[L][l15][quad * 8 + 32 * ks];
        f16x8 a0 = *(const f16x8*)(wb + (5 + ks) * 512);
        f16x8 a1 = *(const f16x8*)(wb + (15 + ks) * 512);
        z0 = __builtin_amdgcn_mfma_f32_16x16x32_f16(a0, bf, z0, 0, 0, 0);
        z1 = __builtin_amdgcn_mfma_f32_16x16x32_f16(a1, bf, z1, 0, 0, 0);
      }
      f16x4 o0;
#pragma unroll
      for (int r = 0; r < 4; ++r) {
        float v = sigm(z0[r] + zg0[L][r]);
        o0[r] = (f16)v;
        if (L == 3) a5o0[r] = v;
      }
      *(f16x4*)&aL[L + 1][l15][t * HC + quad * 4] = o0;
      {
        f16x4 o1;
#pragma unroll
        for (int r = 0; r < 4; ++r) {
          float v = sigm(z1[r] + zg1[L][r]);
          o1[r] = (f16)v;
          if (L == 3) a5o1[r] = v;
        }
        if (quad == 0) *(f16x4*)&aL[L + 1][l15][t * HC + 16] = o1;
      }
      if (L < 3) wsync();  // aL[4] never cross-read before writeout
    }

    // ---- z6: B-frag = fresh a5 only (W6bT zero-masks k>=20) via shfl ----
    {
      unsigned p0 = pk2(a5o0[0], a5o0[1]);
      unsigned p1 = pk2(a5o0[2], a5o0[3]);
      unsigned p2 = pk2(a5o1[0], a5o1[1]);
      unsigned p3 = pk2(a5o1[2], a5o1[3]);
      int src1 = (((quad * 2) & 3) << 4) + l15;
      int src2 = src1 + 16;
      unsigned d0 = (unsigned)__shfl((int)p0, src1, 64);
      unsigned d1 = (unsigned)__shfl((int)p1, src1, 64);
      unsigned d2 = (unsigned)__shfl((int)p0, src2, 64);
      unsigned d3 = (unsigned)__shfl((int)p1, src2, 64);
      unsigned e0 = (unsigned)__shfl((int)p2, src1, 64);
      unsigned e1 = (unsigned)__shfl((int)p3, src1, 64);
      u32x4 bv = (quad < 2) ? (u32x4){d0, d1, d2, d3} : (u32x4){e0, e1, e0, e1};
      f16x8 b5 = __builtin_bit_cast(f16x8, bv);
      f16x8 a6 = *(const f16x8*)(W6bT + (size_t)(m * 8 + t) * 512 + lane * 8);
      acc6 = __builtin_amdgcn_mfma_f32_16x16x32_f16(a6, b5, acc6, 0, 0, 0);
      // extract row t (owner quad = t>>2, reg t&3; static under unroll)
      float x = sigm(acc6[t & 3]);
      if (quad == (t >> 2)) {
        outp[(size_t)bg * NS + i] = x;  // final output col i == sampling-time x
        sL[l15][i] = (f16)((x >= uv[t]) ? 1.0f : -1.0f);
      }
      float xall = __shfl(x, ((t >> 2) << 4) + l15, 64);
      bitv = (xall >= uv[t]) ? 1.0f : -1.0f;
    }
    // no end-of-t sync: t+1 L1 gets the fresh bit from bitv; older sL writes
    // are >= 4 wsyncs old; aL[4] writes only read after the final wsync.
  }
  wsync();

  // ---- bulk writeout: block activations -> global AH ([L][g][b][e]), s bits ----
  for (int w = lane; w < 5 * 20 * BT; w += 64) {
    int rr = w & 15;
    int q = w >> 4;            // 0..99
    int L = q / 20, x8 = q % 20;
    f16x8 v = *(const f16x8*)&aL[L][rr][x8 * 8];
    int gg = ((HC * I) >> 3) + x8;
    *(f16x8*)(AH + ((size_t)(L * 160 + gg) * BS + blockIdx.x * BT + rr) * 8) = v;
  }
  if (lane < BT) {
    *(f16x8*)(s_ws + (size_t)(blockIdx.x * BT + lane) * NS + I) =
        *(const f16x8*)&sL[lane][I];
  }
}

// ---------------------------------------------------------------------------
extern "C" void kernel_launch(void* const* d_in, const int* in_sizes, int n_in,
                              void* d_out, int out_size, void* d_ws, size_t ws_size,
                              hipStream_t stream) {
  (void)in_sizes; (void)n_in; (void)out_size;
  const float* u  = (const float*)d_in[1];
  const float* W1 = (const float*)d_in[2];
  const float* W2 = (const float*)d_in[3];
  const float* W3 = (const float*)d_in[4];
  const float* W4 = (const float*)d_in[5];
  const float* W5 = (const float*)d_in[6];
  const float* W6 = (const float*)d_in[7];
  float* outp = (float*)d_out;

  const size_t wpTEls  = (size_t)4 * 80 * 40 * 512;      // 6.55M  hist A
  const size_t wsT2Els = (size_t)4 * NS * 2 * 10 * 512;  // 2.62M  seq A (tail+intra)
  const size_t w1TEls  = (size_t)NS * 2 * 2 * 512;       // 131K   seq L1 A
  const size_t w6bTEls = (size_t)64 * 512;               // 33K    seq z6 A
  const size_t w6TEls  = (size_t)8 * 40 * 512;           // 164K   z6 hist A
  const size_t wEls = wpTEls + wsT2Els + w1TEls + w6bTEls + w6TEls;
  const size_t wBytes = wEls * sizeof(f16);

  // per-row: AH 12800 + Zg 2x2560 + Zg6 2x64 + s_ws 128 = 18176 B
  size_t rem = (ws_size > wBytes + 4096) ? (ws_size - wBytes - 4096) : 0;
  long long bs = (long long)(rem / 18176);
  bs = (bs / 64) * 64;
  if (bs > NB) bs = NB;
  if (bs < 64) bs = 64;
  const int BS = (int)bs;
  const size_t ZgN = (size_t)4 * 160 * BS;
  const size_t Zg6N = (size_t)16 * BS;

  f16* WpT   = (f16*)d_ws;
  f16* WsT2  = WpT + wpTEls;
  f16* W1T   = WsT2 + wsT2Els;
  f16* W6bT  = W1T + w1TEls;
  f16* W6T   = W6bT + w6bTEls;
  f16* AH    = W6T + w6TEls;
  float* Zg  = (float*)(AH + (size_t)5 * 160 * BS * 8);
  float* Zg6 = Zg + 2 * ZgN;
  f16* s_ws  = (f16*)(Zg6 + 2 * Zg6N);

  prep<<<dim3(4 * HTOT + NS + 16), dim3(256), 0, stream>>>(
      W1, W2, W3, W4, W5, W6, WpT, WsT2, W1T, W6bT, W6T);

  for (int c0 = 0; c0 < NB; c0 += BS) {
    int nr = NB - c0; if (nr > BS) nr = BS;
    for (int m = 0; m < NS / KB; ++m) {
      const int I = m * KB;
      const float* ZgR = Zg + (size_t)(m & 1) * ZgN;
      float* ZgW = Zg + (size_t)((m + 1) & 1) * ZgN;
      const float* Zg6R = Zg6 + (size_t)(m & 1) * Zg6N;
      float* Zg6W = Zg6 + (size_t)((m + 1) & 1) * Zg6N;
      fused<<<dim3(nr / BT), dim3(512), 0, stream>>>(
          WpT, W6T, WsT2, W1T, W6bT, AH, ZgR, ZgW, Zg6R, Zg6W,
          s_ws, u, outp, I, BS, c0);
    }
  }
}

// Round 9
// 1586.037 us; speedup vs baseline: 1.1243x; 1.1243x over previous
//
#include <hip/hip_runtime.h>

// Autoregressive masked net sampler.
//  - output col i == sampling-time x[:,i]  (masks: out i depends on spins < i only)
//  - spin blocks of KB=8: history part = dense GEMM (MFMA f16), intra-block part
//    sequential per-row (rows independent -> no grid sync).
// R9: split kernels (hist | seq), 1154us, strictly serial on one stream.
// R10/R12: fused hist(m+1) into seq(m) as helper waves; regressed (1700/1783).
//     Diagnosis: compiler snapped to 60-64 VGPR (occupancy heuristic for 8-wave
//     WGs) -> the SEQ wave (needs ~88) spilled on its zero-TLP critical chain.
//     Also R12's tailB LDS (52KB/WG) made full seq residency impossible.
// R13 (this): fix the resource geometry, then the register knob:
//     - WG = 512 thr: waves 0-1 = TWO independent seq column-groups (16 cols each,
//       own LDS half), waves 2-7 = six history-GEMM helpers.
//     - grid nr/32 -> 512 WGs; LDS 2x31.7=63.5KB -> 2 WG/CU -> ALL seq waves
//       resident (1/SIMD, = R9) with 12 helper waves/CU (= R9-hist occupancy).
//     - amdgpu_waves_per_eu(4,4): explicit MAX tells regalloc there's no gain
//       below 128 VGPR -> allocates the ~90 both paths need, no spill.
//     - tailB staging dropped (LDS budget); tail B read direct from AH (L2/L3).
//     - s_setprio(1) on seq waves (real role-split now).

#define NS   64          // spins
#define HC   20          // hidden channels per spin
#define HTOT 1280        // NS*HC
#define NB   16384       // batch
#define KB   8           // spins per block (8 blocks)
#define BT   16          // batch rows per seq wave (MFMA N-tile)

typedef _Float16 f16;
typedef _Float16 f16x2 __attribute__((ext_vector_type(2)));
typedef _Float16 f16x4 __attribute__((ext_vector_type(4)));
typedef _Float16 f16x8 __attribute__((ext_vector_type(8)));
typedef float f32x4 __attribute__((ext_vector_type(4)));
typedef unsigned int u32x4 __attribute__((ext_vector_type(4)));

static __device__ __forceinline__ float sigm(float z) {
  return __builtin_amdgcn_rcpf(1.0f + __expf(-z));
}

static __device__ __forceinline__ unsigned pk2(float a, float b) {
  f16x2 t;
  t[0] = (f16)a;
  t[1] = (f16)b;
  return __builtin_bit_cast(unsigned, t);
}

// intra-wave LDS sync: drain ds ops; memory clobber pins mem-op order.
static __device__ __forceinline__ void wsync() {
  __asm__ volatile("s_waitcnt lgkmcnt(0)" ::: "memory");
}

// ---------------------------------------------------------------------------
// prep: build masked f16 weights, pre-swizzled to MFMA A-fragment order.
// Fragment order: lane = quad*16 + row15, elems 8; col = ks*32 + quad*8 + e.
//  WpT [L][rt=row/16][ks=0..39][512]    row=j_o*20+ch_o, mask j_i<=j_o (hist A)
//  WsT2[L][i][tile][ks=0..9][512]       cols rel to HC*(i&~7)-160 (tail+intra),
//                                       ch padded ->32, col<0 => 0 (seq A)
//  W1T [i][tile][ks=0..1][512]          cols = spins, mask c<i (seq L1 A)
//  W6bT[m*8+t][512]                     16 tp rows x 32 k, mask t<=tp,k<20 (z6 A)
//  W6T [m][ks=0..39][512]               16 tp rows (8 real), mask j_i<=I+tp
// ---------------------------------------------------------------------------
__global__ __launch_bounds__(256) void prep(
    const float* __restrict__ W1, const float* __restrict__ W2,
    const float* __restrict__ W3, const float* __restrict__ W4,
    const float* __restrict__ W5, const float* __restrict__ W6,
    f16* __restrict__ WpT, f16* __restrict__ WsT2, f16* __restrict__ W1T,
    f16* __restrict__ W6bT, f16* __restrict__ W6T) {
  __shared__ float row[HTOT];
  int bid = blockIdx.x;
  if (bid < 4 * HTOT) {
    int L = bid / HTOT, cp = bid % HTOT;
    int j_o = cp / HC, ch_o = cp % HC;
    const float* Wsrc = (L == 0) ? W2 : (L == 1) ? W3 : (L == 2) ? W4 : W5;
    const float* src = Wsrc + (size_t)(ch_o * NS + j_o) * HTOT;
    for (int k = threadIdx.x; k < HTOT; k += 256) row[k] = src[k];
    __syncthreads();
    // WpT: this source row is A-row cp -> rt = cp>>4, row15 = cp&15
    {
      int rt = cp >> 4, rl = cp & 15;
      f16* dwp = WpT + (size_t)(L * 80 + rt) * 40 * 512;
      for (int xp = threadIdx.x; xp < HTOT; xp += 256) {
        int j_i = xp / HC, ch_i = xp % HC;
        f16 v = (f16)((j_i <= j_o) ? row[ch_i * NS + j_i] : 0.0f);
        int ks = xp >> 5, q = (xp >> 3) & 3, e = xp & 7;
        dwp[ks * 512 + (q * 16 + rl) * 8 + e] = v;
      }
    }
    // WsT2: A-row ch_o of spin j_o, cols base HC*(j_o&~7)-160 (prev block + intra)
    {
      int base = HC * (j_o & ~7) - 160;
      int tile = ch_o >> 4, tl = ch_o & 15;
      f16* dws = WsT2 + (size_t)(((L * NS + j_o) * 2 + tile) * 10) * 512;
      for (int kr = threadIdx.x; kr < 320; kr += 256) {
        int xp = base + kr;
        f16 v = (f16)0.0f;
        if (xp >= 0) {
          int j_i = xp / HC, ch_i = xp % HC;
          v = (f16)((j_i <= j_o) ? row[ch_i * NS + j_i] : 0.0f);
        }
        int ks = kr >> 5, q = (kr >> 3) & 3, e = kr & 7;
        dws[ks * 512 + (q * 16 + tl) * 8 + e] = v;
      }
      if (ch_o < 12) {  // zero pad rows ch=20..31 (tile1 rows 4..15)
        int zl = (20 + ch_o) & 15;
        f16* dz = WsT2 + (size_t)(((L * NS + j_o) * 2 + 1) * 10) * 512;
        for (int kr = threadIdx.x; kr < 320; kr += 256) {
          int ks = kr >> 5, q = (kr >> 3) & 3, e = kr & 7;
          dz[ks * 512 + (q * 16 + zl) * 8 + e] = (f16)0.0f;
        }
      }
    }
  } else if (bid < 4 * HTOT + NS) {
    int j_o = bid - 4 * HTOT;
    for (int idx = threadIdx.x; idx < 32 * 64; idx += 256) {
      int ch = idx >> 6, c = idx & 63;
      float v = (ch < HC && c < j_o) ? W1[((size_t)ch * NS + j_o) * NS + c] : 0.0f;
      int tile = ch >> 4, tl = ch & 15, ks = c >> 5, q = (c >> 3) & 3, e = c & 7;
      W1T[(size_t)((j_o * 2 + tile) * 2 + ks) * 512 + (q * 16 + tl) * 8 + e] = (f16)v;
    }
  } else if (bid < 4 * HTOT + NS + 8) {
    int m = bid - (4 * HTOT + NS);
    int I = m * KB;
    for (int idx = threadIdx.x; idx < 8 * 16 * 32; idx += 256) {
      int t = idx >> 9, tp = (idx >> 5) & 15, k = idx & 31;
      float v = (tp < 8 && k < HC && t <= tp)
                    ? W6[(size_t)(I + tp) * HTOT + k * NS + (I + t)]
                    : 0.0f;
      int q = k >> 3, e = k & 7;
      W6bT[(size_t)(m * 8 + t) * 512 + (q * 16 + tp) * 8 + e] = (f16)v;
    }
  } else {
    int m = bid - (4 * HTOT + NS + 8);
    int I = m * KB;
    for (int idx = threadIdx.x; idx < 16 * HTOT; idx += 256) {
      int tp = idx / HTOT, xp = idx % HTOT;
      int j_i = xp / HC, ch_i = xp % HC;
      float v = (tp < 8 && j_i <= I + tp)
                    ? W6[(size_t)(I + tp) * HTOT + ch_i * NS + j_i]
                    : 0.0f;
      int ks = xp >> 5, q = (xp >> 3) & 3, e = xp & 7;
      W6T[(size_t)(m * 40 + ks) * 512 + (q * 16 + tp) * 8 + e] = (f16)v;
    }
  }
}

// ---------------------------------------------------------------------------
// fused: waves 0-1 = seq for block m (2 x 16 batch cols, independent, own LDS
// half); waves 2-7 = history GEMM for block m+1 over k < 160*m.
//  seq: Zg(m) [blocks 0..m-2, from ZgR] post-added + per-phase 5-ks tail over
//       block m-1 with B-frags read direct from AH (L2/L3-resident).
//  helpers: units = hist tiles (4L x 2 rowhalves x nr/32 cols) + z6 (nr/64).
// ---------------------------------------------------------------------------
__attribute__((amdgpu_waves_per_eu(4, 4)))
__global__ __launch_bounds__(512) void fused(
    const f16* __restrict__ WpT, const f16* __restrict__ W6T,
    const f16* __restrict__ WsT2, const f16* __restrict__ W1T,
    const f16* __restrict__ W6bT, f16* __restrict__ AH,
    const float* __restrict__ ZgR, float* __restrict__ ZgW,
    const float* __restrict__ Zg6R, float* __restrict__ Zg6W,
    f16* __restrict__ s_ws, const float* __restrict__ u,
    float* __restrict__ outp, int I, int BS, int b0) {
  __shared__ __align__(16) f16 aL[2][5][BT][184];   // 2 x 29440 B
  __shared__ __align__(16) f16 sL[2][BT][72];       // 2 x 2304 B -> 63488 B total

  const int wid = threadIdx.x >> 6;
  const int lane = threadIdx.x & 63;
  const int l15 = lane & 15;
  const int quad = lane >> 4;
  const int m = I >> 3;
  const int G32 = (HC * I) >> 5;   // k-steps over blocks 0..m-1
  const int nr = gridDim.x * 32;

  if (wid >= 2) {
    // ================= helper waves: Zg(m+1)/Zg6(m+1) =================
    if (I >= NS - KB || G32 == 0) return;  // no next block / empty history
    const int NH = 6 * gridDim.x;
    const int per = nr >> 5;          // 32-col tiles per (L, wm)
    const int UH = nr >> 2;           // 4L * 2wm * per
    const int UZ = nr >> 6;           // z6 units (64 cols each)
    int hid = blockIdx.x * 6 + wid - 2;
    for (int uu = hid; uu < UH + UZ; uu += NH) {
      if (uu < UH) {
        const int L = uu / (2 * per);
        const int r2 = uu % (2 * per);
        const int wm = r2 / per;
        const int bc = (r2 % per) * 32;
        f32x4 acc[5][2];
#pragma unroll
        for (int mt = 0; mt < 5; ++mt) {
          acc[mt][0] = (f32x4){0.f, 0.f, 0.f, 0.f};
          acc[mt][1] = (f32x4){0.f, 0.f, 0.f, 0.f};
        }
        const f16* ap =
            WpT + (size_t)((L * 80 + 10 * (m + 1) + 5 * wm) * 40) * 512 + lane * 8;
        const f16* bp = AH + ((size_t)(L * 160 + quad) * BS + bc + l15) * 8;
#pragma unroll 2
        for (int ks = 0; ks < G32; ++ks) {
          f16x8 bf0 = *(const f16x8*)(bp);
          f16x8 bf1 = *(const f16x8*)(bp + 128);
          f16x8 af[5];
#pragma unroll
          for (int mt = 0; mt < 5; ++mt)
            af[mt] = *(const f16x8*)(ap + (size_t)mt * 40 * 512);
#pragma unroll
          for (int mt = 0; mt < 5; ++mt) {
            acc[mt][0] = __builtin_amdgcn_mfma_f32_16x16x32_f16(af[mt], bf0, acc[mt][0], 0, 0, 0);
            acc[mt][1] = __builtin_amdgcn_mfma_f32_16x16x32_f16(af[mt], bf1, acc[mt][1], 0, 0, 0);
          }
          ap += 512;
          bp += (size_t)4 * BS * 8;
        }
#pragma unroll
        for (int mt = 0; mt < 5; ++mt)
#pragma unroll
          for (int nt = 0; nt < 2; ++nt)
#pragma unroll
            for (int r = 0; r < 4; ++r)
              ZgW[(size_t)(L * 160 + wm * 80 + mt * 16 + quad * 4 + r) * BS +
                  bc + nt * 16 + l15] = acc[mt][nt][r];
      } else {
        const int v = uu - UH;
#pragma unroll
        for (int b16 = 0; b16 < 4; ++b16) {
          const int bc = v * 64 + b16 * 16;
          f32x4 acc = (f32x4){0.f, 0.f, 0.f, 0.f};
          const f16* ap = W6T + (size_t)((m + 1) * 40) * 512 + lane * 8;
          const f16* bp = AH + ((size_t)(4 * 160 + quad) * BS + bc + l15) * 8;
#pragma unroll 2
          for (int ks = 0; ks < G32; ++ks) {
            acc = __builtin_amdgcn_mfma_f32_16x16x32_f16(
                *(const f16x8*)ap, *(const f16x8*)bp, acc, 0, 0, 0);
            ap += 512;
            bp += (size_t)4 * BS * 8;
          }
#pragma unroll
          for (int r = 0; r < 4; ++r)
            Zg6W[(size_t)(quad * 4 + r) * BS + bc + l15] = acc[r];
        }
      }
    }
    return;
  }

  // ===================== seq waves (wid = 0, 1) =======================
  __builtin_amdgcn_s_setprio(1);  // critical chain; helpers are throughput waves

  const int sw = wid;                       // seq slot, own LDS half
  const int colbase = blockIdx.x * 32 + sw * BT;
  const int bcol = colbase + l15;
  const int bg = b0 + bcol;
  const int gP = 20 * (m - 1);  // AH g-base of prev block (tail B)

  // early global loads: u for all 8 spins, z6 accumulator init
  float uv[KB];
#pragma unroll
  for (int t = 0; t < KB; ++t) uv[t] = u[(size_t)(I + t) * NB + bg];
  f32x4 acc6 = (f32x4){0.f, 0.f, 0.f, 0.f};
  if (m >= 2) {
#pragma unroll
    for (int r = 0; r < 4; ++r)
      acc6[r] = Zg6R[(size_t)(quad * 4 + r) * BS + bcol];
  }
  if (m >= 1) {  // z6 tail: block m-1 via W6T[m] slab [5(m-1),5m)
    const f16* a6p = W6T + ((size_t)(m * 40) + 5 * (m - 1)) * 512 + lane * 8;
#pragma unroll
    for (int ks = 0; ks < 5; ++ks) {
      f16x8 bf = *(const f16x8*)(AH + ((size_t)(4 * 160 + gP + 4 * ks + quad) * BS + bcol) * 8);
      f16x8 af = *(const f16x8*)(a6p + ks * 512);
      acc6 = __builtin_amdgcn_mfma_f32_16x16x32_f16(af, bf, acc6, 0, 0, 0);
    }
  }

  // zero LDS (masked-weight / K-pad tails must read as 0)
  {
    f16x8 z = {};
    f16x8* pa = (f16x8*)&aL[sw][0][0][0];
    for (int k = lane; k < (5 * BT * 184) / 8; k += 64) pa[k] = z;
    f16x8* ps = (f16x8*)&sL[sw][0][0];
    for (int k = lane; k < (BT * 72) / 8; k += 64) ps[k] = z;
  }
  wsync();

  // load sampled-bit history j < I
  for (int c8 = quad; c8 < (I >> 3); c8 += 4) {
    f16x8 v = *(const f16x8*)(s_ws + (size_t)(colbase + l15) * NS + c8 * 8);
    *(f16x8*)&sL[sw][l15][c8 * 8] = v;
  }
  wsync();

  float bitv = 0.0f;  // freshest sampled bit (spin I+t-1), per batch-column

#pragma unroll
  for (int t = 0; t < KB; ++t) {
    const int i = I + t;

    // ---- prefetch this t's Zg rows for all 4 hidden layers (post-added) ----
    float zg0[4][4], zg1[4][4];
#pragma unroll
    for (int L = 0; L < 4; ++L)
#pragma unroll
      for (int r = 0; r < 4; ++r) {
        zg0[L][r] = (m >= 2)
            ? ZgR[(size_t)(L * 160 + t * HC + quad * 4 + r) * BS + bcol] : 0.f;
        zg1[L][r] = (m >= 2 && quad == 0)
            ? ZgR[(size_t)(L * 160 + t * HC + 16 + r) * BS + bcol] : 0.f;
      }

    // ---- layer 1: z[32ch x 16b] = W1(i) (32x64) . sL (64x16) ----
    {
      f32x4 z0 = (f32x4){0.f, 0.f, 0.f, 0.f};
      f32x4 z1 = (f32x4){0.f, 0.f, 0.f, 0.f};
      const int KS1 = (i + 31) >> 5;
      const f16* w0 = W1T + (size_t)(i * 2) * 2 * 512 + lane * 8;
      for (int ks = 0; ks < KS1; ++ks) {
        f16x8 bf = *(const f16x8*)&sL[sw][l15][quad * 8 + 32 * ks];
        if (t > 0 && ks == ((i - 1) >> 5) && quad == (((I & 31) + t - 1) >> 3))
          bf[(t - 1) & 7] = (f16)bitv;  // freshest bit, not yet LDS-visible
        f16x8 a0 = *(const f16x8*)(w0 + ks * 512);
        f16x8 a1 = *(const f16x8*)(w0 + (2 + ks) * 512);
        z0 = __builtin_amdgcn_mfma_f32_16x16x32_f16(a0, bf, z0, 0, 0, 0);
        z1 = __builtin_amdgcn_mfma_f32_16x16x32_f16(a1, bf, z1, 0, 0, 0);
      }
      f16x4 o0;
#pragma unroll
      for (int r = 0; r < 4; ++r) o0[r] = (f16)sigm(z0[r]);
      *(f16x4*)&aL[sw][0][l15][t * HC + quad * 4] = o0;
      if (quad == 0) {
        f16x4 o1;
#pragma unroll
        for (int r = 0; r < 4; ++r) o1[r] = (f16)sigm(z1[r]);
        *(f16x4*)&aL[sw][0][l15][t * HC + 16] = o1;
      }
    }
    wsync();

    // ---- layers 2..5: z = tail(block m-1, B from AH) + intra + Zg ----
    const int KS = (HC * (t + 1) + 31) >> 5;  // compile-time under unroll
    float a5o0[4], a5o1[4];
#pragma unroll
    for (int L = 0; L < 4; ++L) {
      f32x4 z0 = (f32x4){0.f, 0.f, 0.f, 0.f};
      f32x4 z1 = (f32x4){0.f, 0.f, 0.f, 0.f};
      const f16* wb = WsT2 + (size_t)((L * NS + i) * 2) * 10 * 512 + lane * 8;
      if (m >= 1) {  // tail: 5 ks, B direct from AH (prev block, L2/L3-hot)
#pragma unroll
        for (int ks = 0; ks < 5; ++ks) {
          f16x8 bf = *(const f16x8*)(AH + ((size_t)(L * 160 + gP + 4 * ks + quad) * BS + bcol) * 8);
          f16x8 a0 = *(const f16x8*)(wb + ks * 512);
          f16x8 a1 = *(const f16x8*)(wb + (10 + ks) * 512);
          z0 = __builtin_amdgcn_mfma_f32_16x16x32_f16(a0, bf, z0, 0, 0, 0);
          z1 = __builtin_amdgcn_mfma_f32_16x16x32_f16(a1, bf, z1, 0, 0, 0);
        }
      }
#pragma unroll
      for (int ks = 0; ks < KS; ++ks) {
        f16x8 bf = *(const f16x8*)&aL[sw][L][l15][quad * 8 + 32 * ks];
        f16x8 a0 = *(const f16x8*)(wb + (5 + ks) * 512);
        f16x8 a1 = *(const f16x8*)(wb + (15 + ks) * 512);
        z0 = __builtin_amdgcn_mfma_f32_16x16x32_f16(a0, bf, z0, 0, 0, 0);
        z1 = __builtin_amdgcn_mfma_f32_16x16x32_f16(a1, bf, z1, 0, 0, 0);
      }
      f16x4 o0;
#pragma unroll
      for (int r = 0; r < 4; ++r) {
        float v = sigm(z0[r] + zg0[L][r]);
        o0[r] = (f16)v;
        if (L == 3) a5o0[r] = v;
      }
      *(f16x4*)&aL[sw][L + 1][l15][t * HC + quad * 4] = o0;
      {
        f16x4 o1;
#pragma unroll
        for (int r = 0; r < 4; ++r) {
          float v = sigm(z1[r] + zg1[L][r]);
          o1[r] = (f16)v;
          if (L == 3) a5o1[r] = v;
        }
        if (quad == 0) *(f16x4*)&aL[sw][L + 1][l15][t * HC + 16] = o1;
      }
      if (L < 3) wsync();  // aL[4] never cross-read before writeout
    }

    // ---- z6: B-frag = fresh a5 only (W6bT zero-masks k>=20) via shfl ----
    {
      unsigned p0 = pk2(a5o0[0], a5o0[1]);
      unsigned p1 = pk2(a5o0[2], a5o0[3]);
      unsigned p2 = pk2(a5o1[0], a5o1[1]);
      unsigned p3 = pk2(a5o1[2], a5o1[3]);
      int src1 = (((quad * 2) & 3) << 4) + l15;
      int src2 = src1 + 16;
      unsigned d0 = (unsigned)__shfl((int)p0, src1, 64);
      unsigned d1 = (unsigned)__shfl((int)p1, src1, 64);
      unsigned d2 = (unsigned)__shfl((int)p0, src2, 64);
      unsigned d3 = (unsigned)__shfl((int)p1, src2, 64);
      unsigned e0 = (unsigned)__shfl((int)p2, src1, 64);
      unsigned e1 = (unsigned)__shfl((int)p3, src1, 64);
      u32x4 bv = (quad < 2) ? (u32x4){d0, d1, d2, d3} : (u32x4){e0, e1, e0, e1};
      f16x8 b5 = __builtin_bit_cast(f16x8, bv);
      f16x8 a6 = *(const f16x8*)(W6bT + (size_t)(m * 8 + t) * 512 + lane * 8);
      acc6 = __builtin_amdgcn_mfma_f32_16x16x32_f16(a6, b5, acc6, 0, 0, 0);
      // extract row t (owner quad = t>>2, reg t&3; static under unroll)
      float x = sigm(acc6[t & 3]);
      if (quad == (t >> 2)) {
        outp[(size_t)bg * NS + i] = x;  // final output col i == sampling-time x
        sL[sw][l15][i] = (f16)((x >= uv[t]) ? 1.0f : -1.0f);
      }
      float xall = __shfl(x, ((t >> 2) << 4) + l15, 64);
      bitv = (xall >= uv[t]) ? 1.0f : -1.0f;
    }
    // no end-of-t sync: t+1 L1 gets the fresh bit from bitv; older sL writes
    // are >= 4 wsyncs old; aL[4] writes only read after the final wsync.
  }
  wsync();

  // ---- bulk writeout: block activations -> global AH ([L][g][b][e]), s bits ----
  for (int w = lane; w < 5 * 20 * BT; w += 64) {
    int rr = w & 15;
    int q = w >> 4;            // 0..99
    int L = q / 20, x8 = q % 20;
    f16x8 v = *(const f16x8*)&aL[sw][L][rr][x8 * 8];
    int gg = ((HC * I) >> 3) + x8;
    *(f16x8*)(AH + ((size_t)(L * 160 + gg) * BS + colbase + rr) * 8) = v;
  }
  if (lane < BT) {
    *(f16x8*)(s_ws + (size_t)(colbase + lane) * NS + I) =
        *(const f16x8*)&sL[sw][lane][I];
  }
}

// ---------------------------------------------------------------------------
extern "C" void kernel_launch(void* const* d_in, const int* in_sizes, int n_in,
                              void* d_out, int out_size, void* d_ws, size_t ws_size,
                              hipStream_t stream) {
  (void)in_sizes; (void)n_in; (void)out_size;
  const float* u  = (const float*)d_in[1];
  const float* W1 = (const float*)d_in[2];
  const float* W2 = (const float*)d_in[3];
  const float* W3 = (const float*)d_in[4];
  const float* W4 = (const float*)d_in[5];
  const float* W5 = (const float*)d_in[6];
  const float* W6 = (const float*)d_in[7];
  float* outp = (float*)d_out;

  const size_t wpTEls  = (size_t)4 * 80 * 40 * 512;      // 6.55M  hist A
  const size_t wsT2Els = (size_t)4 * NS * 2 * 10 * 512;  // 2.62M  seq A (tail+intra)
  const size_t w1TEls  = (size_t)NS * 2 * 2 * 512;       // 131K   seq L1 A
  const size_t w6bTEls = (size_t)64 * 512;               // 33K    seq z6 A
  const size_t w6TEls  = (size_t)8 * 40 * 512;           // 164K   z6 hist A
  const size_t wEls = wpTEls + wsT2Els + w1TEls + w6bTEls + w6TEls;
  const size_t wBytes = wEls * sizeof(f16);

  // per-row: AH 12800 + Zg 2x2560 + Zg6 2x64 + s_ws 128 = 18176 B
  size_t rem = (ws_size > wBytes + 4096) ? (ws_size - wBytes - 4096) : 0;
  long long bs = (long long)(rem / 18176);
  bs = (bs / 64) * 64;
  if (bs > NB) bs = NB;
  if (bs < 64) bs = 64;
  const int BS = (int)bs;
  const size_t ZgN = (size_t)4 * 160 * BS;
  const size_t Zg6N = (size_t)16 * BS;

  f16* WpT   = (f16*)d_ws;
  f16* WsT2  = WpT + wpTEls;
  f16* W1T   = WsT2 + wsT2Els;
  f16* W6bT  = W1T + w1TEls;
  f16* W6T   = W6bT + w6bTEls;
  f16* AH    = W6T + w6TEls;
  float* Zg  = (float*)(AH + (size_t)5 * 160 * BS * 8);
  float* Zg6 = Zg + 2 * ZgN;
  f16* s_ws  = (f16*)(Zg6 + 2 * Zg6N);

  prep<<<dim3(4 * HTOT + NS + 16), dim3(256), 0, stream>>>(
      W1, W2, W3, W4, W5, W6, WpT, WsT2, W1T, W6bT, W6T);

  for (int c0 = 0; c0 < NB; c0 += BS) {
    int nr = NB - c0; if (nr > BS) nr = BS;
    for (int m = 0; m < NS / KB; ++m) {
      const int I = m * KB;
      const float* ZgR = Zg + (size_t)(m & 1) * ZgN;
      float* ZgW = Zg + (size_t)((m + 1) & 1) * ZgN;
      const float* Zg6R = Zg6 + (size_t)(m & 1) * Zg6N;
      float* Zg6W = Zg6 + (size_t)((m + 1) & 1) * Zg6N;
      fused<<<dim3(nr / 32), dim3(512), 0, stream>>>(
          WpT, W6T, WsT2, W1T, W6bT, AH, ZgR, ZgW, Zg6R, Zg6W,
          s_ws, u, outp, I, BS, c0);
    }
  }
}

// Round 10
// 1448.918 us; speedup vs baseline: 1.2307x; 1.0946x over previous
//
#include <hip/hip_runtime.h>

// Autoregressive masked net sampler.
//  - output col i == sampling-time x[:,i]  (masks: out i depends on spins < i only)
//  - spin blocks of KB=8: history part = dense GEMM (MFMA f16), intra-block part
//    sequential per-row (rows independent -> no grid sync).
// R9: split kernels (hist | seq), 1154us verified. R10-R13: single-kernel fusion
//     abandoned -- compiler caps 8-wave WGs at 60-64 VGPR (3 knobs tried), the
//     ~90-VGPR seq wave spills on its zero-TLP chain. Falsifier honored.
// R14 (this): back to R9 split + two targeted fixes:
//  hist: K-split x2 (blockIdx.z) -> 1280 blocks, 20 waves/CU (was 10, Occ 37%);
//        per-wave MFMA:load ratio unchanged; Zg/Zg6 become 2 partials summed by seq.
//  seq:  ROLL the t-loop (R9's full unroll = ~128KB code streamed through each CU's
//        32KB I$ at 1 wave/SIMD -- seq FETCH 44MB vs ~24MB data = icache signature).
//        Fixed KS=5 phases (masked weights x zeroed LDS keep it exact) make the body
//        fully static; sampled bit passes through sL + end-of-t lgkmcnt; two-bank
//        (pA/pB) one-phase-ahead weight prefetch + rotated Zg-bank prefetch issued
//        in source order (crosses wsync by issue, not compiler motion).

#define NS   64          // spins
#define HC   20          // hidden channels per spin
#define HTOT 1280        // NS*HC
#define NB   16384       // batch
#define KB   8           // spins per block (8 blocks)
#define BT   16          // batch rows per seq wave (MFMA N-tile)

typedef _Float16 f16;
typedef _Float16 f16x2 __attribute__((ext_vector_type(2)));
typedef _Float16 f16x4 __attribute__((ext_vector_type(4)));
typedef _Float16 f16x8 __attribute__((ext_vector_type(8)));
typedef float f32x4 __attribute__((ext_vector_type(4)));
typedef unsigned int u32x4 __attribute__((ext_vector_type(4)));

static __device__ __forceinline__ float sigm(float z) {
  return __builtin_amdgcn_rcpf(1.0f + __expf(-z));
}

static __device__ __forceinline__ unsigned pk2(float a, float b) {
  f16x2 t;
  t[0] = (f16)a;
  t[1] = (f16)b;
  return __builtin_bit_cast(unsigned, t);
}

// intra-wave LDS sync: drain ds ops; memory clobber pins mem-op order.
static __device__ __forceinline__ void wsync() {
  __asm__ volatile("s_waitcnt lgkmcnt(0)" ::: "memory");
}

// ---------------------------------------------------------------------------
// prep: build masked f16 weights, pre-swizzled to MFMA A-fragment order.
// Fragment order: lane = quad*16 + row15, elems 8; col = ks*32 + quad*8 + e.
//  WpT [L][rt=row/16][ks=0..39][512]    row=j_o*20+ch_o, mask j_i<=j_o (hist A)
//  WsT [L][i][tile=ch/16][ks=0..4][512] cols rel to HC*(i&~7), ch padded ->32 (seq A)
//  W1T [i][tile][ks=0..1][512]          cols = spins, mask c<i (seq L1 A)
//  W6bT[m*8+t][512]                     16 tp rows x 32 k, mask t<=tp,k<20 (z6 A)
//  W6T [m][ks=0..39][512]               16 tp rows (8 real), mask j_i<=I+tp
// ---------------------------------------------------------------------------
__global__ __launch_bounds__(256) void prep(
    const float* __restrict__ W1, const float* __restrict__ W2,
    const float* __restrict__ W3, const float* __restrict__ W4,
    const float* __restrict__ W5, const float* __restrict__ W6,
    f16* __restrict__ WpT, f16* __restrict__ WsT, f16* __restrict__ W1T,
    f16* __restrict__ W6bT, f16* __restrict__ W6T) {
  __shared__ float row[HTOT];
  int bid = blockIdx.x;
  if (bid < 4 * HTOT) {
    int L = bid / HTOT, cp = bid % HTOT;
    int j_o = cp / HC, ch_o = cp % HC;
    const float* Wsrc = (L == 0) ? W2 : (L == 1) ? W3 : (L == 2) ? W4 : W5;
    const float* src = Wsrc + (size_t)(ch_o * NS + j_o) * HTOT;
    for (int k = threadIdx.x; k < HTOT; k += 256) row[k] = src[k];
    __syncthreads();
    // WpT: this source row is A-row cp -> rt = cp>>4, row15 = cp&15
    {
      int rt = cp >> 4, rl = cp & 15;
      f16* dwp = WpT + (size_t)(L * 80 + rt) * 40 * 512;
      for (int xp = threadIdx.x; xp < HTOT; xp += 256) {
        int j_i = xp / HC, ch_i = xp % HC;
        f16 v = (f16)((j_i <= j_o) ? row[ch_i * NS + j_i] : 0.0f);
        int ks = xp >> 5, q = (xp >> 3) & 3, e = xp & 7;
        dwp[ks * 512 + (q * 16 + rl) * 8 + e] = v;
      }
    }
    // WsT: A-row ch_o of spin j_o, cols relative to block base HC*(j_o&~7)
    {
      int base = HC * (j_o & ~7);
      int tile = ch_o >> 4, tl = ch_o & 15;
      f16* dws = WsT + (size_t)(((L * NS + j_o) * 2 + tile) * 5) * 512;
      for (int kr = threadIdx.x; kr < 160; kr += 256) {
        int xp = base + kr;
        int j_i = xp / HC, ch_i = xp % HC;
        f16 v = (f16)((j_i <= j_o) ? row[ch_i * NS + j_i] : 0.0f);
        int ks = kr >> 5, q = (kr >> 3) & 3, e = kr & 7;
        dws[ks * 512 + (q * 16 + tl) * 8 + e] = v;
      }
      if (ch_o < 12) {  // zero pad rows ch=20..31 (tile1 rows 4..15)
        int zl = (20 + ch_o) & 15;
        f16* dz = WsT + (size_t)(((L * NS + j_o) * 2 + 1) * 5) * 512;
        for (int kr = threadIdx.x; kr < 160; kr += 256) {
          int ks = kr >> 5, q = (kr >> 3) & 3, e = kr & 7;
          dz[ks * 512 + (q * 16 + zl) * 8 + e] = (f16)0.0f;
        }
      }
    }
  } else if (bid < 4 * HTOT + NS) {
    int j_o = bid - 4 * HTOT;
    for (int idx = threadIdx.x; idx < 32 * 64; idx += 256) {
      int ch = idx >> 6, c = idx & 63;
      float v = (ch < HC && c < j_o) ? W1[((size_t)ch * NS + j_o) * NS + c] : 0.0f;
      int tile = ch >> 4, tl = ch & 15, ks = c >> 5, q = (c >> 3) & 3, e = c & 7;
      W1T[(size_t)((j_o * 2 + tile) * 2 + ks) * 512 + (q * 16 + tl) * 8 + e] = (f16)v;
    }
  } else if (bid < 4 * HTOT + NS + 8) {
    int m = bid - (4 * HTOT + NS);
    int I = m * KB;
    for (int idx = threadIdx.x; idx < 8 * 16 * 32; idx += 256) {
      int t = idx >> 9, tp = (idx >> 5) & 15, k = idx & 31;
      float v = (tp < 8 && k < HC && t <= tp)
                    ? W6[(size_t)(I + tp) * HTOT + k * NS + (I + t)]
                    : 0.0f;
      int q = k >> 3, e = k & 7;
      W6bT[(size_t)(m * 8 + t) * 512 + (q * 16 + tp) * 8 + e] = (f16)v;
    }
  } else {
    int m = bid - (4 * HTOT + NS + 8);
    int I = m * KB;
    for (int idx = threadIdx.x; idx < 16 * HTOT; idx += 256) {
      int tp = idx / HTOT, xp = idx % HTOT;
      int j_i = xp / HC, ch_i = xp % HC;
      float v = (tp < 8 && j_i <= I + tp)
                    ? W6[(size_t)(I + tp) * HTOT + ch_i * NS + j_i]
                    : 0.0f;
      int ks = xp >> 5, q = (xp >> 3) & 3, e = xp & 7;
      W6T[(size_t)(m * 40 + ks) * 512 + (q * 16 + tp) * 8 + e] = (f16)v;
    }
  }
}

// ---------------------------------------------------------------------------
// gemm_hist: history GEMMs for block at spin I; K-split x2 via blockIdx.z.
//  L<4 : ZgP[z][L][c][b]  partial over ks in [ks0, ks0+kn)
//  L==4: Zg6P[z][tp][b]   same split for the layer-6 rows
// A loads coalesced from fragment-order WpT/W6T; AH is raw B-fragment layout.
// Grid (nr/64, 5, 2) x 256 thr -> 2x blocks of R9 = 20 waves/CU.
// ---------------------------------------------------------------------------
__global__ __launch_bounds__(256) void gemm_hist(
    const f16* __restrict__ WpT, const f16* __restrict__ W6T,
    const f16* __restrict__ AH, float* __restrict__ Zg,
    float* __restrict__ Zg6, int I, int BS) {
  const int L = blockIdx.y;
  const int z = blockIdx.z;
  const int tid = threadIdx.x;
  const int lane = tid & 63;
  const int w = tid >> 6;
  const int l15 = tid & 15;
  const int quad = lane >> 4;
  const int m = I >> 3;
  const int G32 = (HC * I) >> 5;
  const int H0 = G32 >> 1;
  const int ks0 = z ? H0 : 0;
  const int kn = z ? (G32 - H0) : H0;
  float* ZgP = Zg + (size_t)z * 640 * BS;
  float* Zg6P = Zg6 + (size_t)z * 16 * BS;

  if (L == 4) {
    const int b0 = blockIdx.x * 64 + w * 16;
    f32x4 acc = (f32x4){0.f, 0.f, 0.f, 0.f};
    const f16* ap = W6T + ((size_t)(m * 40) + ks0) * 512 + lane * 8;
    const f16* bp = AH + ((size_t)(4 * 160 + 4 * ks0 + quad) * BS + b0 + l15) * 8;
#pragma unroll 2
    for (int ks = 0; ks < kn; ++ks) {
      f16x8 af = *(const f16x8*)ap;
      f16x8 bf = *(const f16x8*)bp;
      acc = __builtin_amdgcn_mfma_f32_16x16x32_f16(af, bf, acc, 0, 0, 0);
      ap += 512;
      bp += (size_t)4 * BS * 8;
    }
#pragma unroll
    for (int r = 0; r < 4; ++r)
      Zg6P[(size_t)(quad * 4 + r) * BS + b0 + l15] = acc[r];
    return;
  }

  const int wm = w & 1, wn = w >> 1;
  const int b0 = blockIdx.x * 64 + wn * 32;

  f32x4 acc[5][2];
#pragma unroll
  for (int mt = 0; mt < 5; ++mt) {
    acc[mt][0] = (f32x4){0.f, 0.f, 0.f, 0.f};
    acc[mt][1] = (f32x4){0.f, 0.f, 0.f, 0.f};
  }

  const f16* ap =
      WpT + ((size_t)((L * 80 + 10 * m + 5 * wm) * 40) + ks0) * 512 + lane * 8;
  const f16* bp = AH + ((size_t)(L * 160 + 4 * ks0 + quad) * BS + b0 + l15) * 8;

#pragma unroll 2
  for (int ks = 0; ks < kn; ++ks) {
    f16x8 bf0 = *(const f16x8*)(bp);
    f16x8 bf1 = *(const f16x8*)(bp + 128);
    f16x8 af[5];
#pragma unroll
    for (int mt = 0; mt < 5; ++mt)
      af[mt] = *(const f16x8*)(ap + (size_t)mt * 40 * 512);
#pragma unroll
    for (int mt = 0; mt < 5; ++mt) {
      acc[mt][0] = __builtin_amdgcn_mfma_f32_16x16x32_f16(af[mt], bf0, acc[mt][0], 0, 0, 0);
      acc[mt][1] = __builtin_amdgcn_mfma_f32_16x16x32_f16(af[mt], bf1, acc[mt][1], 0, 0, 0);
    }
    ap += 512;
    bp += (size_t)4 * BS * 8;
  }

#pragma unroll
  for (int mt = 0; mt < 5; ++mt)
#pragma unroll
    for (int nt = 0; nt < 2; ++nt)
#pragma unroll
      for (int r = 0; r < 4; ++r) {
        int c = wm * 80 + mt * 16 + quad * 4 + r;
        int b = b0 + nt * 16 + l15;
        ZgP[(size_t)(L * 160 + c) * BS + b] = acc[mt][nt][r];
      }
}

// ---------------------------------------------------------------------------
// seq_block v8 (rolled t-loop, static phases, two-bank prefetch): 1 wave,
// BT=16 batch cols. Per t: L1 (2 fixed ks) then 4 phases of 5 fixed ks each
// (zero-padded weights x zeroed LDS make over-K exact). Weights for phase L+1
// prefetched during phase L (banks pA/pB); Zg partial-sums prefetched one
// phase ahead (banks zA/zB); z6 via shfl from layer-5 C-regs; sampled bit
// passes through sL with one end-of-t lgkmcnt.
// ---------------------------------------------------------------------------
__global__ __launch_bounds__(64) void seq_block(
    const f16* __restrict__ WsT, const f16* __restrict__ W1T,
    const f16* __restrict__ W6bT, f16* __restrict__ AH,
    const float* __restrict__ Zg, const float* __restrict__ Zg6,
    f16* __restrict__ s_ws, const float* __restrict__ u,
    float* __restrict__ outp, int I, int BS, int b0) {
  __shared__ __align__(16) f16 aL[5][BT][184];   // 29440 B
  __shared__ __align__(16) f16 sL[BT][72];       // 2304 B -> 31744 B total

  const int lane = threadIdx.x;
  const int l15 = lane & 15;            // MFMA col = batch row in WG
  const int quad = lane >> 4;           // MFMA k-group / C row-group
  const int m = I >> 3;
  const int bcol = blockIdx.x * BT + l15;
  const int bg = b0 + bcol;
  const size_t ZgPN = (size_t)640 * BS;    // K-split partial stride
  const size_t Zg6PN = (size_t)16 * BS;

  // z6 accumulator: sum of the two K-split history partials
  f32x4 acc6;
#pragma unroll
  for (int r = 0; r < 4; ++r) {
    size_t o = (size_t)(quad * 4 + r) * BS + bcol;
    acc6[r] = Zg6[o] + Zg6[Zg6PN + o];
  }

  // prologue weight prefetch: phase-L0 bank + L1 weights for t=0
  f16x8 pA[10], pB[10], w1r[4];
  {
    const f16* wb = WsT + (size_t)((0 * NS + I) * 2) * 5 * 512 + lane * 8;
#pragma unroll
    for (int k = 0; k < 5; ++k) {
      pA[k] = *(const f16x8*)(wb + k * 512);
      pA[5 + k] = *(const f16x8*)(wb + (5 + k) * 512);
    }
    const f16* w1p = W1T + (size_t)(I * 2) * 2 * 512 + lane * 8;
#pragma unroll
    for (int k = 0; k < 2; ++k) {
      w1r[k] = *(const f16x8*)(w1p + k * 512);
      w1r[2 + k] = *(const f16x8*)(w1p + (2 + k) * 512);
    }
  }

  // zero LDS (masked-weight / K-pad tails must read as 0)
  {
    f16x8 zz = {};
    f16x8* pa = (f16x8*)&aL[0][0][0];
    for (int k = lane; k < (5 * BT * 184) / 8; k += 64) pa[k] = zz;
    f16x8* ps = (f16x8*)&sL[0][0];
    for (int k = lane; k < (BT * 72) / 8; k += 64) ps[k] = zz;
  }
  wsync();

  // load sampled-bit history j < I
  for (int c8 = quad; c8 < (I >> 3); c8 += 4) {
    f16x8 v = *(const f16x8*)(s_ws + (size_t)(blockIdx.x * BT + l15) * NS + c8 * 8);
    *(f16x8*)&sL[l15][c8 * 8] = v;
  }
  wsync();

  float zA0[4], zA1[4], zB0[4], zB1[4];
  float a5o0[4], a5o1[4];

#define ZGLOAD(BK0, BK1, Lv)                                                   \
  {                                                                            \
    _Pragma("unroll") for (int r = 0; r < 4; ++r) {                            \
      size_t o0_ = (size_t)((Lv) * 160 + t * HC + quad * 4 + r) * BS + bcol;   \
      BK0[r] = Zg[o0_] + Zg[ZgPN + o0_];                                       \
      size_t o1_ = (size_t)((Lv) * 160 + t * HC + 16 + r) * BS + bcol;         \
      BK1[r] = (quad == 0) ? (Zg[o1_] + Zg[ZgPN + o1_]) : 0.f;                 \
    }                                                                          \
  }

#define PHASE(Lv, CUR, NXT, NPTR, ZV0, ZV1, CAP)                               \
  {                                                                            \
    const f16* nw_ = (NPTR);                                                   \
    _Pragma("unroll") for (int k = 0; k < 5; ++k) {                            \
      NXT[k] = *(const f16x8*)(nw_ + k * 512);                                 \
      NXT[5 + k] = *(const f16x8*)(nw_ + (5 + k) * 512);                       \
    }                                                                          \
    f32x4 z0_ = (f32x4){0.f, 0.f, 0.f, 0.f};                                   \
    f32x4 z1_ = (f32x4){0.f, 0.f, 0.f, 0.f};                                   \
    _Pragma("unroll") for (int k = 0; k < 5; ++k) {                            \
      f16x8 bf_ = *(const f16x8*)&aL[Lv][l15][quad * 8 + 32 * k];              \
      z0_ = __builtin_amdgcn_mfma_f32_16x16x32_f16(CUR[k], bf_, z0_, 0, 0, 0); \
      z1_ = __builtin_amdgcn_mfma_f32_16x16x32_f16(CUR[5 + k], bf_, z1_, 0, 0, 0);\
    }                                                                          \
    f16x4 o0_;                                                                 \
    _Pragma("unroll") for (int r = 0; r < 4; ++r) {                            \
      float v_ = sigm(z0_[r] + ZV0[r]);                                        \
      o0_[r] = (f16)v_;                                                        \
      if (CAP) a5o0[r] = v_;                                                   \
    }                                                                          \
    *(f16x4*)&aL[(Lv) + 1][l15][t * HC + quad * 4] = o0_;                      \
    {                                                                          \
      f16x4 o1_;                                                               \
      _Pragma("unroll") for (int r = 0; r < 4; ++r) {                          \
        float v_ = sigm(z1_[r] + ZV1[r]);                                      \
        o1_[r] = (f16)v_;                                                      \
        if (CAP) a5o1[r] = v_;                                                 \
      }                                                                        \
      if (quad == 0) *(f16x4*)&aL[(Lv) + 1][l15][t * HC + 16] = o1_;           \
    }                                                                          \
    wsync();                                                                   \
  }

  for (int t = 0; t < KB; ++t) {
    const int i = I + t;
    const int inext = (t < KB - 1) ? i + 1 : i;  // capped: last prefetch unused

    float uvt = u[(size_t)i * NB + bg];
    f16x8 a6 = *(const f16x8*)(W6bT + (size_t)(m * 8 + t) * 512 + lane * 8);
    ZGLOAD(zA0, zA1, 0)
    ZGLOAD(zB0, zB1, 1)

    // ---- layer 1: fixed 2 K-steps (masked weights / zeroed sL) ----
    {
      f32x4 z0 = (f32x4){0.f, 0.f, 0.f, 0.f};
      f32x4 z1 = (f32x4){0.f, 0.f, 0.f, 0.f};
#pragma unroll
      for (int k = 0; k < 2; ++k) {
        f16x8 bf = *(const f16x8*)&sL[l15][quad * 8 + 32 * k];
        z0 = __builtin_amdgcn_mfma_f32_16x16x32_f16(w1r[k], bf, z0, 0, 0, 0);
        z1 = __builtin_amdgcn_mfma_f32_16x16x32_f16(w1r[2 + k], bf, z1, 0, 0, 0);
      }
      f16x4 o0;
#pragma unroll
      for (int r = 0; r < 4; ++r) o0[r] = (f16)sigm(z0[r]);
      *(f16x4*)&aL[0][l15][t * HC + quad * 4] = o0;
      if (quad == 0) {
        f16x4 o1;
#pragma unroll
        for (int r = 0; r < 4; ++r) o1[r] = (f16)sigm(z1[r]);
        *(f16x4*)&aL[0][l15][t * HC + 16] = o1;
      }
    }
    wsync();

    // ---- phases: layer L+2 uses bank loaded during previous phase ----
    PHASE(0, pA, pB,
          WsT + (size_t)((1 * NS + i) * 2) * 5 * 512 + lane * 8, zA0, zA1, 0)
    ZGLOAD(zA0, zA1, 2)
    PHASE(1, pB, pA,
          WsT + (size_t)((2 * NS + i) * 2) * 5 * 512 + lane * 8, zB0, zB1, 0)
    ZGLOAD(zB0, zB1, 3)
    PHASE(2, pA, pB,
          WsT + (size_t)((3 * NS + i) * 2) * 5 * 512 + lane * 8, zA0, zA1, 0)
    {  // refill L1 weights for next t (issued before phase 3's MFMAs)
      const f16* w1n = W1T + (size_t)(inext * 2) * 2 * 512 + lane * 8;
#pragma unroll
      for (int k = 0; k < 2; ++k) {
        w1r[k] = *(const f16x8*)(w1n + k * 512);
        w1r[2 + k] = *(const f16x8*)(w1n + (2 + k) * 512);
      }
    }
    PHASE(3, pB, pA,
          WsT + (size_t)((0 * NS + inext) * 2) * 5 * 512 + lane * 8, zB0, zB1, 1)

    // ---- z6: B-frag = fresh a5 only (W6bT zero-masks k>=20) via shfl ----
    {
      unsigned p0 = pk2(a5o0[0], a5o0[1]);
      unsigned p1 = pk2(a5o0[2], a5o0[3]);
      unsigned p2 = pk2(a5o1[0], a5o1[1]);
      unsigned p3 = pk2(a5o1[2], a5o1[3]);
      int src1 = (((quad * 2) & 3) << 4) + l15;
      int src2 = src1 + 16;
      unsigned d0 = (unsigned)__shfl((int)p0, src1, 64);
      unsigned d1 = (unsigned)__shfl((int)p1, src1, 64);
      unsigned d2 = (unsigned)__shfl((int)p0, src2, 64);
      unsigned d3 = (unsigned)__shfl((int)p1, src2, 64);
      unsigned e0 = (unsigned)__shfl((int)p2, src1, 64);
      unsigned e1 = (unsigned)__shfl((int)p3, src1, 64);
      u32x4 bv = (quad < 2) ? (u32x4){d0, d1, d2, d3} : (u32x4){e0, e1, e0, e1};
      f16x8 b5 = __builtin_bit_cast(f16x8, bv);
      acc6 = __builtin_amdgcn_mfma_f32_16x16x32_f16(a6, b5, acc6, 0, 0, 0);
      int r3 = t & 3;
      float vs = r3 == 0 ? acc6[0] : r3 == 1 ? acc6[1] : r3 == 2 ? acc6[2] : acc6[3];
      float x = sigm(vs);
      if (quad == (t >> 2)) {
        outp[(size_t)bg * NS + i] = x;  // final output col i == sampling-time x
        sL[l15][i] = (f16)((x >= uvt) ? 1.0f : -1.0f);
      }
    }
    wsync();  // sL bit visible to next t's L1 (same-wave lgkmcnt ordering)
  }
#undef ZGLOAD
#undef PHASE

  // ---- bulk writeout: block activations -> global AH ([L][g][b][e]), s bits ----
  for (int w = lane; w < 5 * 20 * BT; w += 64) {
    int rr = w & 15;
    int q = w >> 4;            // 0..99
    int L = q / 20, x8 = q % 20;
    f16x8 v = *(const f16x8*)&aL[L][rr][x8 * 8];
    int gg = ((HC * I) >> 3) + x8;
    *(f16x8*)(AH + ((size_t)(L * 160 + gg) * BS + blockIdx.x * BT + rr) * 8) = v;
  }
  if (lane < BT) {
    *(f16x8*)(s_ws + (size_t)(blockIdx.x * BT + lane) * NS + I) =
        *(const f16x8*)&sL[lane][I];
  }
}

// ---------------------------------------------------------------------------
extern "C" void kernel_launch(void* const* d_in, const int* in_sizes, int n_in,
                              void* d_out, int out_size, void* d_ws, size_t ws_size,
                              hipStream_t stream) {
  (void)in_sizes; (void)n_in; (void)out_size;
  const float* u  = (const float*)d_in[1];
  const float* W1 = (const float*)d_in[2];
  const float* W2 = (const float*)d_in[3];
  const float* W3 = (const float*)d_in[4];
  const float* W4 = (const float*)d_in[5];
  const float* W5 = (const float*)d_in[6];
  const float* W6 = (const float*)d_in[7];
  float* outp = (float*)d_out;

  const size_t wpTEls  = (size_t)4 * 80 * 40 * 512;      // 6.55M  hist A
  const size_t wsTEls  = (size_t)4 * NS * 2 * 5 * 512;   // 1.31M  seq A
  const size_t w1TEls  = (size_t)NS * 2 * 2 * 512;       // 131K   seq L1 A
  const size_t w6bTEls = (size_t)64 * 512;               // 33K    seq z6 A
  const size_t w6TEls  = (size_t)8 * 40 * 512;           // 164K   hist z6 A
  const size_t wEls = wpTEls + wsTEls + w1TEls + w6bTEls + w6TEls;
  const size_t wBytes = wEls * sizeof(f16);

  // per-row: AH 12800 + Zg 2x2560 + Zg6 2x64 + s_ws 128 = 18176 B
  size_t rem = (ws_size > wBytes + 4096) ? (ws_size - wBytes - 4096) : 0;
  long long bs = (long long)(rem / 18176);
  bs = (bs / 64) * 64;
  if (bs > NB) bs = NB;
  if (bs < 64) bs = 64;
  const int BS = (int)bs;

  f16* WpT   = (f16*)d_ws;
  f16* WsT   = WpT + wpTEls;
  f16* W1T   = WsT + wsTEls;
  f16* W6bT  = W1T + w1TEls;
  f16* W6T   = W6bT + w6bTEls;
  f16* AH    = W6T + w6TEls;
  float* Zg  = (float*)(AH + (size_t)5 * 160 * BS * 8);
  float* Zg6 = Zg + (size_t)2 * 640 * BS;
  f16* s_ws  = (f16*)(Zg6 + (size_t)2 * 16 * BS);

  prep<<<dim3(4 * HTOT + NS + 16), dim3(256), 0, stream>>>(
      W1, W2, W3, W4, W5, W6, WpT, WsT, W1T, W6bT, W6T);

  for (int c0 = 0; c0 < NB; c0 += BS) {
    int nr = NB - c0; if (nr > BS) nr = BS;
    for (int m = 0; m < NS / KB; ++m) {
      const int I = m * KB;
      gemm_hist<<<dim3(nr / 64, 5, 2), dim3(256), 0, stream>>>(
          WpT, W6T, AH, Zg, Zg6, I, BS);
      seq_block<<<dim3(nr / BT), dim3(64), 0, stream>>>(
          WsT, W1T, W6bT, AH, Zg, Zg6, s_ws, u, outp, I, BS, c0);
    }
  }
}